// Round 1
// baseline (2815.483 us; speedup 1.0000x reference)
//
#include <hip/hip_runtime.h>
#include <hip/hip_bf16.h>
#include <math.h>

#define B_ 4
#define N_ 8192
#define MD_ 512
#define H_ 8
#define F_ 16
#define S_ 32
#define S3_ 32768
#define L_ 256
#define CO_ 152   // H*(F+3)
#define HF_ 128   // H*F
#define EPS_ 1e-5f

// ---------------- zero kernel (z lattice must be zeroed every launch) -------
__global__ __launch_bounds__(256) void zero_kernel(float4* __restrict__ p, int n4) {
    int i = blockIdx.x * 256 + threadIdx.x;
    if (i < n4) p[i] = make_float4(0.f, 0.f, 0.f, 0.f);
}

// ---------------- style projections: h = style @ W.T + b --------------------
__global__ __launch_bounds__(256) void style_proj(
    const float* __restrict__ style,
    const float* __restrict__ kw_w, const float* __restrict__ kw_b,
    const float* __restrict__ vw_w, const float* __restrict__ vw_b,
    const float* __restrict__ aw_w, const float* __restrict__ aw_b,
    float* __restrict__ hk, float* __restrict__ hv, float* __restrict__ ha) {
    int b = blockIdx.x;
    const float* st = style + b * L_;
    for (int r = threadIdx.x; r < 48 + 256 + 256; r += 256) {
        const float* wrow; float bias; float* dst; int j;
        if (r < 48)       { j = r;       wrow = kw_w + j * L_; bias = kw_b[j]; dst = hk + b * 48; }
        else if (r < 304) { j = r - 48;  wrow = vw_w + j * L_; bias = vw_b[j]; dst = hv + b * 256; }
        else              { j = r - 304; wrow = aw_w + j * L_; bias = aw_b[j]; dst = ha + b * 256; }
        float acc = bias;
        for (int l = 0; l < L_; ++l) acc = fmaf(st[l], wrow[l], acc);
        dst[j] = acc;
    }
}

// ---------------- conv-weight transpose to [h][ic][tap][oc] -----------------
__global__ __launch_bounds__(256) void wtrans(const float* __restrict__ cw, float* __restrict__ wt) {
    int i = blockIdx.x * 256 + threadIdx.x;   // 8*16*27*16 = 55296 total
    if (i >= H_ * F_ * 27 * F_) return;
    int oc  = i & 15;
    int tap = (i >> 4) % 27;
    int rest = (i >> 4) / 27;    // h*16 + ic
    int ic = rest & 15;
    int h  = rest >> 4;
    wt[i] = cw[(((h * 16 + oc) * 16 + ic) * 27) + tap];
}

// ---------------- kv = W_kv @ input  (per batch) ----------------------------
// grid (8 n-blocks, 8 row-blocks, 4 batch); block 256; each thread 4 n, 19 rows
__global__ __launch_bounds__(256) void kv_gemm(
    const float* __restrict__ input, const float* __restrict__ Wkv, float* __restrict__ kv) {
    int b = blockIdx.z, rb = blockIdx.y;
    int n0 = blockIdx.x * 1024 + (threadIdx.x << 2);
    __shared__ float wlds[19 * MD_];
    for (int i = threadIdx.x; i < 19 * MD_ / 4; i += 256)
        ((float4*)wlds)[i] = ((const float4*)(Wkv + rb * 19 * MD_))[i];
    __syncthreads();
    float acc[19][4];
    #pragma unroll
    for (int i = 0; i < 19; ++i)
        for (int q = 0; q < 4; ++q) acc[i][q] = 0.f;
    const float* inb = input + (size_t)b * MD_ * N_ + n0;
    for (int c = 0; c < MD_; ++c) {
        float4 x = *(const float4*)(inb + (size_t)c * N_);
        #pragma unroll
        for (int i = 0; i < 19; ++i) {
            float w = wlds[i * MD_ + c];
            acc[i][0] = fmaf(w, x.x, acc[i][0]);
            acc[i][1] = fmaf(w, x.y, acc[i][1]);
            acc[i][2] = fmaf(w, x.z, acc[i][2]);
            acc[i][3] = fmaf(w, x.w, acc[i][3]);
        }
    }
    float* outb = kv + (size_t)b * CO_ * N_ + n0;
    #pragma unroll
    for (int i = 0; i < 19; ++i)
        *(float4*)(outb + (size_t)(rb * 19 + i) * N_) =
            make_float4(acc[i][0], acc[i][1], acc[i][2], acc[i][3]);
}

// ---------------- per-(b,channel) mean / rsig over N ------------------------
__global__ __launch_bounds__(256) void stats_kernel(
    const float* __restrict__ x, float* __restrict__ mean, float* __restrict__ rsig) {
    int bc = blockIdx.x;
    const float* p = x + (size_t)bc * N_;
    float s = 0.f, s2 = 0.f;
    for (int i = threadIdx.x; i < N_; i += 256) {
        float v = p[i]; s += v; s2 = fmaf(v, v, s2);
    }
    #pragma unroll
    for (int off = 32; off; off >>= 1) { s += __shfl_down(s, off); s2 += __shfl_down(s2, off); }
    __shared__ float ls[4], ls2[4];
    int wid = threadIdx.x >> 6;
    if ((threadIdx.x & 63) == 0) { ls[wid] = s; ls2[wid] = s2; }
    __syncthreads();
    if (threadIdx.x == 0) {
        float S = ls[0] + ls[1] + ls[2] + ls[3];
        float S2 = ls2[0] + ls2[1] + ls2[2] + ls2[3];
        float mu = S * (1.f / N_);
        float var = S2 * (1.f / N_) - mu * mu;
        mean[bc] = mu;
        rsig[bc] = rsqrtf(var + EPS_);
    }
}

// ---------------- point kernel: AdaIN(keys)+transform+tanh+interp+splat -----
// grid 1024, block 256; thread -> p = bh*N + n
__global__ __launch_bounds__(256) void point_splat(
    const float* __restrict__ kv, const float* __restrict__ mean_kv,
    const float* __restrict__ rsig_kv, const float* __restrict__ hk,
    const float* __restrict__ hv, const float* __restrict__ orig,
    const float* __restrict__ scale_p, const float* __restrict__ Tw,
    const float* __restrict__ Tb, float* __restrict__ z,
    int* __restrict__ idxbuf, float* __restrict__ wbuf) {
    int p = blockIdx.x * 256 + threadIdx.x;
    int n = p & (N_ - 1);
    int bh = p >> 13;
    int h = bh & 7, b = bh >> 3;
    float scl = scale_p[0];

    float pt[3];
    #pragma unroll
    for (int j = 0; j < 3; ++j) {
        int c = h * 3 + j;
        float x  = kv[((size_t)(b * CO_ + c)) * N_ + n];
        float xn = (x - mean_kv[b * CO_ + c]) * rsig_kv[b * CO_ + c];
        float kr = fmaf(1.f + hk[b * 48 + c], xn, hk[b * 48 + 24 + c]);
        pt[j] = fmaf(scl, kr, orig[((size_t)(b * 3 + j)) * N_ + n]);
    }
    int f0[3]; float tt[3];
    #pragma unroll
    for (int i = 0; i < 3; ++i) {
        float key = Tb[h * 3 + i];
        #pragma unroll
        for (int j = 0; j < 3; ++j) key = fmaf(Tw[(h * 3 + i) * 3 + j], pt[j], key);
        float lat = tanhf(key);
        float g = (lat + 1.f) * 0.5f * (float)(S_ - 1);
        float ff = floorf(g);
        ff = fminf(fmaxf(ff, 0.f), 30.f);
        f0[i] = (int)ff;
        tt[i] = fminf(fmaxf(g - ff, 0.f), 1.f);
    }
    int cidx[8]; float cwt[8];
    #pragma unroll
    for (int k = 0; k < 8; ++k) {
        int cx = (k >> 2) & 1, cy = (k >> 1) & 1, cz = k & 1;
        cidx[k] = ((f0[0] + cx) * S_ + f0[1] + cy) * S_ + f0[2] + cz;
        cwt[k] = (cx ? tt[0] : 1.f - tt[0]) * (cy ? tt[1] : 1.f - tt[1]) * (cz ? tt[2] : 1.f - tt[2]);
        idxbuf[((size_t)(bh * 8 + k)) * N_ + n] = cidx[k];
        wbuf  [((size_t)(bh * 8 + k)) * N_ + n] = cwt[k];
    }
    float* zb = z + (size_t)bh * F_ * S3_;
    #pragma unroll
    for (int f = 0; f < F_; ++f) {
        int c = 24 + h * F_ + f;            // kv channel
        float x  = kv[((size_t)(b * CO_ + c)) * N_ + n];
        float xn = (x - mean_kv[b * CO_ + c]) * rsig_kv[b * CO_ + c];
        int cv = h * F_ + f;                // value channel
        float val = fmaf(1.f + hv[b * 256 + cv], xn, hv[b * 256 + 128 + cv]);
        #pragma unroll
        for (int k = 0; k < 8; ++k)
            atomicAdd(zb + (size_t)f * S3_ + cidx[k], val * cwt[k]);
    }
}

// ---------------- grouped 3x3x3 conv over the lattice -----------------------
// grid 4096, block 256; thread -> one voxel, all 16 out channels of its group
__global__ __launch_bounds__(256) void conv3d(
    const float* __restrict__ zin, const float* __restrict__ wt,
    const float* __restrict__ cb, float* __restrict__ zout) {
    int p = blockIdx.x * 256 + threadIdx.x;
    int v = p & (S3_ - 1);
    int bh = p >> 15;
    int h = bh & 7;
    int zc = v & 31, yc = (v >> 5) & 31, xc = v >> 10;
    const float* wg = wt + (size_t)h * 16 * 27 * 16;
    const float* inb = zin + (size_t)bh * F_ * S3_;
    float acc[16];
    #pragma unroll
    for (int o = 0; o < 16; ++o) acc[o] = 0.f;
    for (int i = 0; i < 16; ++i) {
        const float* inc = inb + (size_t)i * S3_;
        const float* wi = wg + i * 27 * 16;
        #pragma unroll
        for (int dx = 0; dx < 3; ++dx) {
            int xx = xc + dx - 1;
            if (xx < 0 || xx > 31) continue;    // block-uniform branch
            #pragma unroll
            for (int dy = 0; dy < 3; ++dy) {
                int yy = yc + dy - 1;
                bool oky = (yy >= 0) && (yy <= 31);
                #pragma unroll
                for (int dz = 0; dz < 3; ++dz) {
                    int zz = zc + dz - 1;
                    bool ok = oky && (zz >= 0) && (zz <= 31);
                    float inv = ok ? inc[(xx * 32 + yy) * 32 + zz] : 0.f;
                    const float* wtap = wi + ((dx * 3 + dy) * 3 + dz) * 16;
                    #pragma unroll
                    for (int o = 0; o < 16; ++o) acc[o] = fmaf(inv, wtap[o], acc[o]);
                }
            }
        }
    }
    float* outb = zout + (size_t)bh * F_ * S3_;
    #pragma unroll
    for (int o = 0; o < 16; ++o)
        outb[(size_t)o * S3_ + v] = acc[o] + cb[h * 16 + o];
}

// ---------------- slice: weighted gather back to points ---------------------
__global__ __launch_bounds__(256) void slice_kernel(
    const float* __restrict__ zc, const int* __restrict__ idxbuf,
    const float* __restrict__ wbuf, float* __restrict__ out) {
    int p = blockIdx.x * 256 + threadIdx.x;
    int n = p & (N_ - 1);
    int bh = p >> 13;
    int h = bh & 7, b = bh >> 3;
    int cidx[8]; float cwt[8];
    #pragma unroll
    for (int k = 0; k < 8; ++k) {
        cidx[k] = idxbuf[((size_t)(bh * 8 + k)) * N_ + n];
        cwt[k]  = wbuf  [((size_t)(bh * 8 + k)) * N_ + n];
    }
    const float* gb = zc + (size_t)bh * F_ * S3_;
    #pragma unroll
    for (int f = 0; f < F_; ++f) {
        float acc = 0.f;
        #pragma unroll
        for (int k = 0; k < 8; ++k)
            acc = fmaf(cwt[k], gb[(size_t)f * S3_ + cidx[k]], acc);
        out[((size_t)(b * HF_ + h * F_ + f)) * N_ + n] = acc;
    }
}

// ---------------- final AdaIN + ReLU (in place on d_out) --------------------
__global__ __launch_bounds__(256) void final_adain(
    float* __restrict__ out, const float* __restrict__ mean_o,
    const float* __restrict__ rsig_o, const float* __restrict__ ha) {
    size_t i = (size_t)blockIdx.x * 256 + threadIdx.x;  // 4*128*8192 total
    int bc = (int)(i >> 13);        // b*128 + c
    int c = bc & 127, b = bc >> 7;
    float x = out[i];
    float xn = (x - mean_o[bc]) * rsig_o[bc];
    float y = fmaf(1.f + ha[b * 256 + c], xn, ha[b * 256 + 128 + c]);
    out[i] = fmaxf(y, 0.f);
}

extern "C" void kernel_launch(void* const* d_in, const int* in_sizes, int n_in,
                              void* d_out, int out_size, void* d_ws, size_t ws_size,
                              hipStream_t stream) {
    (void)in_sizes; (void)n_in; (void)out_size; (void)ws_size;
    const float* input   = (const float*)d_in[0];
    const float* style   = (const float*)d_in[1];
    const float* orig    = (const float*)d_in[2];
    const float* Wkv     = (const float*)d_in[3];
    const float* kw_w    = (const float*)d_in[4];
    const float* kw_b    = (const float*)d_in[5];
    const float* vw_w    = (const float*)d_in[6];
    const float* vw_b    = (const float*)d_in[7];
    const float* aw_w    = (const float*)d_in[8];
    const float* aw_b    = (const float*)d_in[9];
    const float* scale_p = (const float*)d_in[10];
    const float* Tw      = (const float*)d_in[11];
    const float* Tb      = (const float*)d_in[12];
    const float* conv_w  = (const float*)d_in[13];
    const float* conv_b  = (const float*)d_in[14];
    float* out = (float*)d_out;

    // -------- workspace layout (floats). Region B (kv chain) is dead before
    // conv writes zc, so zc aliases it.  Total ~151.2 MB.
    float* ws = (float*)d_ws;
    float* z       = ws;                               // 16,777,216
    int*   idxbuf  = (int*)(ws + 16777216);            //  2,097,152 ints
    float* wbuf    = ws + 16777216 + 2097152;          //  2,097,152
    float* wt      = wbuf + 2097152;                   //     55,296
    float* ha      = wt + 55296;                       //      1,024
    float* mean_o  = ha + 1024;                        //        512
    float* rsig_o  = mean_o + 512;                     //        512
    float* kv      = rsig_o + 512;                     //  4,980,736  (region B)
    float* mean_kv = kv + 4980736;                     //        608
    float* rsig_kv = mean_kv + 608;                    //        608
    float* hk      = rsig_kv + 608;                    //        192
    float* hv      = hk + 192;                         //      1,024
    float* zc      = kv;                               // 16,777,216  (aliases region B)

    // 1. zero the splat lattice (must happen every launch)
    zero_kernel<<<16384, 256, 0, stream>>>((float4*)z, 16777216 / 4);
    // 2. style projections + conv-weight transpose (independent, tiny)
    style_proj<<<B_, 256, 0, stream>>>(style, kw_w, kw_b, vw_w, vw_b, aw_w, aw_b, hk, hv, ha);
    wtrans<<<216, 256, 0, stream>>>(conv_w, wt);
    // 3. kv GEMM
    kv_gemm<<<dim3(8, 8, B_), 256, 0, stream>>>(input, Wkv, kv);
    // 4. instance-norm stats for all 152 kv channels
    stats_kernel<<<B_ * CO_, 256, 0, stream>>>(kv, mean_kv, rsig_kv);
    // 5. keys AdaIN + transform + tanh + trilinear interp + splat (atomics)
    point_splat<<<B_ * H_ * N_ / 256, 256, 0, stream>>>(
        kv, mean_kv, rsig_kv, hk, hv, orig, scale_p, Tw, Tb, z, idxbuf, wbuf);
    // 6. grouped 3x3x3 conv over lattice (kv region dead now; zc aliases it)
    conv3d<<<B_ * H_ * S3_ / 256, 256, 0, stream>>>(z, wt, conv_b, zc);
    // 7. slice (weighted gather) -> raw features into d_out
    slice_kernel<<<B_ * H_ * N_ / 256, 256, 0, stream>>>(zc, idxbuf, wbuf, out);
    // 8. final AdaIN stats + normalize + ReLU in place
    stats_kernel<<<B_ * HF_, 256, 0, stream>>>(out, mean_o, rsig_o);
    final_adain<<<B_ * HF_ * N_ / 256, 256, 0, stream>>>(out, mean_o, rsig_o, ha);
}